// Round 1
// baseline (2200.830 us; speedup 1.0000x reference)
//
#include <hip/hip_runtime.h>
#include <math.h>

#define H_DIM 512
#define GROUPS_PER_BLOCK 8      // (b,i) groups per block
#define ROWS 48                 // 6 * GROUPS_PER_BLOCK
#define KT 16                   // K-tile
#define THREADS 256

// -------------------------------------------------------------------------
// Kernel 1: prop = relu(app @ Wp + bp) -> out[..., 0:512]
// app[b,i,:] = ctx[b, i*4+2 .. i*4+3]
// memory-bound: 117 MB of stores
// -------------------------------------------------------------------------
__global__ __launch_bounds__(256) void prop_kernel(
    const float* __restrict__ ctx, const float* __restrict__ Wp,
    const float* __restrict__ bp, float* __restrict__ out, int total4)
{
    int tid = blockIdx.x * 256 + threadIdx.x;
    if (tid >= total4) return;
    int c4 = tid & 127;          // float4 index within 512 cols (512/4 = 128)
    int gi = tid >> 7;           // g = b*7 + i
    int b = gi / 7;
    int i = gi - b * 7;
    float a0 = ctx[b * 28 + i * 4 + 2];
    float a1 = ctx[b * 28 + i * 4 + 3];
    float4 w0 = ((const float4*)Wp)[c4];            // Wp[0][c..c+3]
    float4 w1 = ((const float4*)(Wp + 512))[c4];    // Wp[1][c..c+3]
    float4 bv = ((const float4*)bp)[c4];
    float4 r;
    r.x = fmaxf(fmaf(a1, w1.x, fmaf(a0, w0.x, bv.x)), 0.f);
    r.y = fmaxf(fmaf(a1, w1.y, fmaf(a0, w0.y, bv.y)), 0.f);
    r.z = fmaxf(fmaf(a1, w1.z, fmaf(a0, w0.z, bv.z)), 0.f);
    r.w = fmaxf(fmaf(a1, w1.w, fmaf(a0, w0.w, bv.w)), 0.f);
    ((float4*)(out + (size_t)gi * 1024))[c4] = r;
}

// -------------------------------------------------------------------------
// Kernel 2: fused feats -> h = relu(feats@W1+b1) -> rel = relu(h@W2+b2)
//           -> mean over j -> out[..., 512:1024]
// Block: 256 threads, 8 groups (48 rows) x 512 cols, K-tiled by 16.
// Per-thread register tile: 12 rows x 8 cols = 96 accumulators.
// -------------------------------------------------------------------------
__global__ __launch_bounds__(256, 2) void rel_kernel(
    const float* __restrict__ ctx, const float* __restrict__ W1,
    const float* __restrict__ b1, const float* __restrict__ W2,
    const float* __restrict__ b2, float* __restrict__ out, int totalG)
{
    __shared__ __align__(16) float feats[ROWS][9];      // 1.7 KB
    __shared__ __align__(16) float hs[KT][ROWS];        // 3 KB, transposed: hs[k][r]
    __shared__ __align__(16) float w2s[KT][H_DIM];      // 32 KB

    const int t = threadIdx.x;
    const int gbase = blockIdx.x * GROUPS_PER_BLOCK;

    // ---- stage feats for the 48 rows of this block ----
    if (t < ROWS) {
        int r = t;
        int G = gbase + (r / 6);
        int jj = r - (r / 6) * 6;
        if (G < totalG) {
            int b = G / 7;
            int i = G - b * 7;
            int j = jj + (jj >= i ? 1 : 0);
            const float* cb = ctx + (size_t)b * 28;
            float xi0 = cb[i*4+0], xi1 = cb[i*4+1], xi2 = cb[i*4+2], xi3 = cb[i*4+3];
            float xj0 = cb[j*4+0], xj1 = cb[j*4+1], xj2 = cb[j*4+2], xj3 = cb[j*4+3];
            float d0 = xi0 - xj0, d1 = xi1 - xj1, d2 = xi2 - xj2, d3 = xi3 - xj3;
            feats[r][0] = xi2; feats[r][1] = xi3;
            feats[r][2] = xj2; feats[r][3] = xj3;
            feats[r][4] = d0;  feats[r][5] = d1;
            feats[r][6] = d2;  feats[r][7] = d3;
            feats[r][8] = sqrtf(d0 * d0 + d1 * d1);
        } else {
            #pragma unroll
            for (int f = 0; f < 9; ++f) feats[r][f] = 0.f;
        }
    }

    const int tx = t & 63;   // col group: cols tx*8 .. tx*8+7
    const int ty = t >> 6;   // row group: rows ty*12 .. ty*12+11

    float acc[12][8];
    #pragma unroll
    for (int r = 0; r < 12; ++r)
        #pragma unroll
        for (int c = 0; c < 8; ++c) acc[r][c] = 0.f;

    __syncthreads();

    for (int kt = 0; kt < H_DIM; kt += KT) {
        // ---- stage h tile (transposed): hs[k][r], 16x48 = 768 elems, 3/thread
        #pragma unroll
        for (int it = 0; it < 3; ++it) {
            int e = t + it * 256;
            int k = e / 48;
            int r = e - k * 48;
            float a = b1[kt + k];
            #pragma unroll
            for (int f = 0; f < 9; ++f)
                a = fmaf(feats[r][f], W1[f * 512 + kt + k], a);
            hs[k][r] = fmaxf(a, 0.f);
        }
        // ---- stage W2 k-slab: rows kt..kt+15, full 512 width (2048 float4)
        const float4* w2g = (const float4*)(W2 + (size_t)kt * 512);
        float4* w2l = (float4*)&w2s[0][0];
        #pragma unroll
        for (int it = 0; it < 8; ++it) {
            int q = t + it * 256;
            w2l[q] = w2g[q];
        }
        __syncthreads();

        // ---- 96 FMAs per k, 16 k per tile ----
        #pragma unroll
        for (int k = 0; k < KT; ++k) {
            float4 h0 = *(const float4*)&hs[k][ty * 12 + 0];
            float4 h1 = *(const float4*)&hs[k][ty * 12 + 4];
            float4 h2 = *(const float4*)&hs[k][ty * 12 + 8];
            float4 w0 = *(const float4*)&w2s[k][tx * 8 + 0];
            float4 w1 = *(const float4*)&w2s[k][tx * 8 + 4];
            float hr[12] = {h0.x, h0.y, h0.z, h0.w,
                            h1.x, h1.y, h1.z, h1.w,
                            h2.x, h2.y, h2.z, h2.w};
            float wc[8]  = {w0.x, w0.y, w0.z, w0.w,
                            w1.x, w1.y, w1.z, w1.w};
            #pragma unroll
            for (int r = 0; r < 12; ++r)
                #pragma unroll
                for (int c = 0; c < 8; ++c)
                    acc[r][c] = fmaf(hr[r], wc[c], acc[r][c]);
        }
        __syncthreads();
    }

    // ---- epilogue: +b2, relu, mean over the 6 j's of each group, store ----
    float bb[8];
    #pragma unroll
    for (int c = 0; c < 8; ++c) bb[c] = b2[tx * 8 + c];

    #pragma unroll
    for (int gg = 0; gg < 2; ++gg) {
        int G = gbase + ty * 2 + gg;
        float p[8];
        #pragma unroll
        for (int c = 0; c < 8; ++c) p[c] = 0.f;
        #pragma unroll
        for (int j = 0; j < 6; ++j) {
            #pragma unroll
            for (int c = 0; c < 8; ++c)
                p[c] += fmaxf(acc[gg * 6 + j][c] + bb[c], 0.f);
        }
        if (G < totalG) {
            float* o = out + (size_t)G * 1024 + 512 + tx * 8;
            float4 v0 = {p[0] * (1.f/6.f), p[1] * (1.f/6.f),
                         p[2] * (1.f/6.f), p[3] * (1.f/6.f)};
            float4 v1 = {p[4] * (1.f/6.f), p[5] * (1.f/6.f),
                         p[6] * (1.f/6.f), p[7] * (1.f/6.f)};
            *(float4*)(o + 0) = v0;
            *(float4*)(o + 4) = v1;
        }
    }
}

extern "C" void kernel_launch(void* const* d_in, const int* in_sizes, int n_in,
                              void* d_out, int out_size, void* d_ws, size_t ws_size,
                              hipStream_t stream) {
    const float* ctx = (const float*)d_in[0];
    const float* W1  = (const float*)d_in[1];
    const float* b1  = (const float*)d_in[2];
    const float* W2  = (const float*)d_in[3];
    const float* b2  = (const float*)d_in[4];
    const float* Wp  = (const float*)d_in[5];
    const float* bp  = (const float*)d_in[6];
    float* out = (float*)d_out;

    int B = in_sizes[0] / 28;           // ctx is (B, 28)
    int totalG = B * 7;                 // (b,i) groups
    int total4 = totalG * 128;          // prop float4 elements
    int blocks1 = (total4 + 255) / 256;
    prop_kernel<<<blocks1, 256, 0, stream>>>(ctx, Wp, bp, out, total4);

    int blocks2 = (totalG + GROUPS_PER_BLOCK - 1) / GROUPS_PER_BLOCK;
    rel_kernel<<<blocks2, THREADS, 0, stream>>>(ctx, W1, b1, W2, b2, out, totalG);
}

// Round 3
// 866.099 us; speedup vs baseline: 2.5411x; 2.5411x over previous
//
#include <hip/hip_runtime.h>
#include <math.h>

typedef __attribute__((ext_vector_type(8))) short bf16x8;
typedef __attribute__((ext_vector_type(4))) float f32x4;

#define THREADS 512
#define MTILE 96
#define BK 32
#define KSTEPS 16
#define NGROUPS 16

// RTN-even fp32 -> bf16 bits
__device__ __forceinline__ ushort f2bf(float f) {
    union { float f; uint u; } x; x.f = f;
    uint r = (x.u + 0x7fffu + ((x.u >> 16) & 1u)) >> 16;
    return (ushort)r;
}

__device__ __forceinline__ void load_lds16(const void* gsrc, void* ldst) {
    __builtin_amdgcn_global_load_lds(
        (const __attribute__((address_space(1))) void*)gsrc,
        (__attribute__((address_space(3))) void*)ldst, 16, 0, 0);
}

// -------------------------------------------------------------------------
// prep: W2 (512x512 f32, [k][n]) -> ws as bf16, transposed to [kstep][n][chunk]
// with chunk pre-XOR-swizzled: ws chunk (kt,n,c_lds) holds k-chunk c_lds ^ ((n>>1)&3).
// Each (kt,n) slot = 32 bf16 = 16 uints.  8192 threads; reads coalesced along n.
// -------------------------------------------------------------------------
__global__ __launch_bounds__(256) void prep_w2(const float* __restrict__ W2,
                                               uint* __restrict__ w2t)
{
    int tid = blockIdx.x * 256 + threadIdx.x;   // 0..8191
    int kt = tid >> 9;                          // 0..15
    int n  = tid & 511;
    uint pk[16];
    #pragma unroll
    for (int k2 = 0; k2 < 16; ++k2) {
        float f0 = W2[(size_t)(kt * 32 + k2 * 2 + 0) * 512 + n];
        float f1 = W2[(size_t)(kt * 32 + k2 * 2 + 1) * 512 + n];
        pk[k2] = (uint)f2bf(f0) | ((uint)f2bf(f1) << 16);
    }
    int sw = (n >> 1) & 3;
    uint* dst = w2t + (size_t)(kt * 512 + n) * 16;  // 32 bf16 = 16 uints per (kt,n)
    #pragma unroll
    for (int c = 0; c < 4; ++c) {
        int kc = c ^ sw;
        uint4 q = { pk[kc*4+0], pk[kc*4+1], pk[kc*4+2], pk[kc*4+3] };
        ((uint4*)dst)[c] = q;
    }
}

// -------------------------------------------------------------------------
// prop = relu(app @ Wp + bp) -> out[..., 0:512]   (memory-bound)
// -------------------------------------------------------------------------
__global__ __launch_bounds__(256) void prop_kernel(
    const float* __restrict__ ctx, const float* __restrict__ Wp,
    const float* __restrict__ bp, float* __restrict__ out, int total4)
{
    int tid = blockIdx.x * 256 + threadIdx.x;
    if (tid >= total4) return;
    int c4 = tid & 127;
    int gi = tid >> 7;
    int b = gi / 7;
    int i = gi - b * 7;
    float a0 = ctx[b * 28 + i * 4 + 2];
    float a1 = ctx[b * 28 + i * 4 + 3];
    float4 w0 = ((const float4*)Wp)[c4];
    float4 w1 = ((const float4*)(Wp + 512))[c4];
    float4 bv = ((const float4*)bp)[c4];
    float4 r;
    r.x = fmaxf(fmaf(a1, w1.x, fmaf(a0, w0.x, bv.x)), 0.f);
    r.y = fmaxf(fmaf(a1, w1.y, fmaf(a0, w0.y, bv.y)), 0.f);
    r.z = fmaxf(fmaf(a1, w1.z, fmaf(a0, w0.z, bv.z)), 0.f);
    r.w = fmaxf(fmaf(a1, w1.w, fmaf(a0, w0.w, bv.w)), 0.f);
    ((float4*)(out + (size_t)gi * 1024))[c4] = r;
}

// -------------------------------------------------------------------------
// rel: fused feats -> h=relu(feats@W1+b1) [fp32, ->bf16] -> MFMA h@W2 -> relu
//      -> mean over j -> out[..., 512:1024]
// 512 thr / 8 waves (2M x 4N), Mtile=96, N=512, BK=32.
// LDS: Bs ring[3] (96KB) + hA ring[3] (18KB) + W1s (18KB) + b1s + feats.
// Single barrier per k-step, counted vmcnt(4). pool[16][512] aliases Bs.
// -------------------------------------------------------------------------
__global__ __launch_bounds__(THREADS, 2) void rel_kernel(
    const float* __restrict__ ctx, const float* __restrict__ W1,
    const float* __restrict__ b1, const uint* __restrict__ w2t,
    const float* __restrict__ b2, float* __restrict__ out, int B)
{
    __shared__ __align__(16) char smem[140672];
    ushort* Bs    = (ushort*)(smem);             // [3][512][4][8] bf16
    ushort* hA    = (ushort*)(smem + 98304);     // [3][96][4][8] bf16
    float*  W1s   = (float*) (smem + 116736);    // [9][512]
    float*  b1s   = (float*) (smem + 135168);    // [512]
    float*  feats = (float*) (smem + 137216);    // [96][9]
    float*  pool  = (float*) (smem);             // [16][512] alias (epilogue)

    const int t   = threadIdx.x;
    const int wid = t >> 6, l = t & 63;
    const int wm  = wid >> 2, wn = wid & 3;
    const int blk = blockIdx.x;
    const int row0 = blk * MTILE;
    const int totalG = B * 7;

    // ---- prologue: issue Bs[0], stage W1/b1/feats ----
    {
        const uint* src = w2t;                       // k-step 0 slab
        #pragma unroll
        for (int it = 0; it < 4; ++it) {
            int e = t + it * 512;
            load_lds16(src + e * 4, Bs + e * 8);
        }
    }
    for (int e = t; e < 9 * 512; e += THREADS) W1s[e] = W1[e];
    if (t < 512) b1s[t] = b1[t];
    if (t < MTILE) {
        int R = row0 + t;
        int G = R / 6, jj = R - G * 6;
        float* fr = feats + t * 9;
        if (G < totalG) {
            int b = G / 7, i = G - b * 7;
            int j = jj + (jj >= i ? 1 : 0);
            const float* cb = ctx + (size_t)b * 28;
            float xi0=cb[i*4], xi1=cb[i*4+1], xi2=cb[i*4+2], xi3=cb[i*4+3];
            float xj0=cb[j*4], xj1=cb[j*4+1], xj2=cb[j*4+2], xj3=cb[j*4+3];
            float d0=xi0-xj0, d1=xi1-xj1, d2=xi2-xj2, d3=xi3-xj3;
            fr[0]=xi2; fr[1]=xi3; fr[2]=xj2; fr[3]=xj3;
            fr[4]=d0;  fr[5]=d1;  fr[6]=d2;  fr[7]=d3;
            fr[8]=sqrtf(d0*d0 + d1*d1);
        } else {
            #pragma unroll
            for (int f = 0; f < 9; ++f) fr[f] = 0.f;
        }
    }
    __syncthreads();   // full drain ok in prologue (also lands Bs[0])

    // ---- h-compute role (waves 0..5): thread -> (row, k-chunk) ----
    const int hr  = t >> 2;                         // 0..95 (valid t<384)
    const int hc  = t & 3;                          // natural k-chunk
    const int hsw = hc ^ ((hr >> 1) & 3);           // swizzled LDS chunk
    float ffr[9];
    if (wid < 6) {
        #pragma unroll
        for (int f = 0; f < 9; ++f) ffr[f] = feats[hr * 9 + f];
    }

    auto computeH = [&](int ks, uint4& pk) {
        int k = ks * BK + hc * 8;
        float4 lo = *(const float4*)(b1s + k);
        float4 hi = *(const float4*)(b1s + k + 4);
        #pragma unroll
        for (int f = 0; f < 9; ++f) {
            float ff = ffr[f];
            float4 w0 = *(const float4*)(W1s + f * 512 + k);
            float4 w1 = *(const float4*)(W1s + f * 512 + k + 4);
            lo.x = fmaf(ff, w0.x, lo.x); lo.y = fmaf(ff, w0.y, lo.y);
            lo.z = fmaf(ff, w0.z, lo.z); lo.w = fmaf(ff, w0.w, lo.w);
            hi.x = fmaf(ff, w1.x, hi.x); hi.y = fmaf(ff, w1.y, hi.y);
            hi.z = fmaf(ff, w1.z, hi.z); hi.w = fmaf(ff, w1.w, hi.w);
        }
        lo.x = fmaxf(lo.x, 0.f); lo.y = fmaxf(lo.y, 0.f);
        lo.z = fmaxf(lo.z, 0.f); lo.w = fmaxf(lo.w, 0.f);
        hi.x = fmaxf(hi.x, 0.f); hi.y = fmaxf(hi.y, 0.f);
        hi.z = fmaxf(hi.z, 0.f); hi.w = fmaxf(hi.w, 0.f);
        pk.x = (uint)f2bf(lo.x) | ((uint)f2bf(lo.y) << 16);
        pk.y = (uint)f2bf(lo.z) | ((uint)f2bf(lo.w) << 16);
        pk.z = (uint)f2bf(hi.x) | ((uint)f2bf(hi.y) << 16);
        pk.w = (uint)f2bf(hi.z) | ((uint)f2bf(hi.w) << 16);
    };

    f32x4 acc[3][8];
    #pragma unroll
    for (int mf = 0; mf < 3; ++mf)
        #pragma unroll
        for (int nf = 0; nf < 8; ++nf)
            acc[mf][nf] = (f32x4){0.f, 0.f, 0.f, 0.f};

    // prologue h: h(0) -> hA[0]; h(1) -> regs
    uint4 hreg = {0,0,0,0};
    if (wid < 6) {
        uint4 p0; computeH(0, p0);
        *(uint4*)(hA + 0 * 3072 + hr * 32 + hsw * 8) = p0;
        computeH(1, hreg);
    }

    // A-frag read addresses (swizzled), per m-frag
    int aoff[3];
    #pragma unroll
    for (int mf = 0; mf < 3; ++mf) {
        int r = wm * 48 + mf * 16 + (l & 15);
        int c = (l >> 4) ^ ((r >> 1) & 3);
        aoff[mf] = r * 32 + c * 8;
    }
    int boff[8];
    #pragma unroll
    for (int nf = 0; nf < 8; ++nf) {
        int n = wn * 128 + nf * 16 + (l & 15);
        int c = (l >> 4) ^ ((n >> 1) & 3);
        boff[nf] = n * 32 + c * 8;
    }

    int ir = 0, iw = 1;
    for (int ks = 0; ks < KSTEPS; ++ks) {
        // phase 1: issue next Bs slab + write next hA
        if (ks + 1 < KSTEPS) {
            const uint* src = w2t + (size_t)(ks + 1) * 8192;
            ushort* dstB = Bs + iw * 16384;
            #pragma unroll
            for (int it = 0; it < 4; ++it) {
                int e = t + it * 512;
                load_lds16(src + e * 4, dstB + e * 8);
            }
            if (wid < 6)
                *(uint4*)(hA + iw * 3072 + hr * 32 + hsw * 8) = hreg;
            asm volatile("s_waitcnt vmcnt(4) lgkmcnt(0)" ::: "memory");
        } else {
            asm volatile("s_waitcnt vmcnt(0) lgkmcnt(0)" ::: "memory");
        }
        __builtin_amdgcn_s_barrier();
        __builtin_amdgcn_sched_barrier(0);

        // phase 2: MFMA on buffers[ir]
        const ushort* hbuf = hA + ir * 3072;
        const ushort* bbuf = Bs + ir * 16384;
        bf16x8 afr[3];
        #pragma unroll
        for (int mf = 0; mf < 3; ++mf)
            afr[mf] = *(const bf16x8*)(hbuf + aoff[mf]);
        __builtin_amdgcn_s_setprio(1);
        #pragma unroll
        for (int nf = 0; nf < 8; ++nf) {
            bf16x8 bfr = *(const bf16x8*)(bbuf + boff[nf]);
            acc[0][nf] = __builtin_amdgcn_mfma_f32_16x16x32_bf16(afr[0], bfr, acc[0][nf], 0, 0, 0);
            acc[1][nf] = __builtin_amdgcn_mfma_f32_16x16x32_bf16(afr[1], bfr, acc[1][nf], 0, 0, 0);
            acc[2][nf] = __builtin_amdgcn_mfma_f32_16x16x32_bf16(afr[2], bfr, acc[2][nf], 0, 0, 0);
        }
        __builtin_amdgcn_s_setprio(0);

        // compute h two steps ahead (overlaps MFMA via VALU pipe)
        if (wid < 6 && ks + 2 < KSTEPS) computeH(ks + 2, hreg);

        ir = ir + 1; if (ir == 3) ir = 0;
        iw = iw + 1; if (iw == 3) iw = 0;
    }

    // ---- epilogue: +b2, relu, mean over 6 j's via LDS pool, store ----
    __syncthreads();                     // all Bs reads done; pool aliases Bs
    #pragma unroll
    for (int i = 0; i < 4; ++i)
        ((float4*)pool)[t + i * 512] = (float4){0.f, 0.f, 0.f, 0.f};
    __syncthreads();

    const float inv6 = 1.0f / 6.0f;
    #pragma unroll
    for (int mf = 0; mf < 3; ++mf) {
        int rbase = wm * 48 + mf * 16 + (l >> 4) * 4;
        #pragma unroll
        for (int nf = 0; nf < 8; ++nf) {
            int col = wn * 128 + nf * 16 + (l & 15);
            float bb = b2[col];
            f32x4 a = acc[mf][nf];
            float run = 0.f;
            int gprev = rbase / 6;
            #pragma unroll
            for (int r = 0; r < 4; ++r) {
                int g = (rbase + r) / 6;
                float vv = fmaxf(a[r] + bb, 0.f) * inv6;
                if (g != gprev) {
                    atomicAdd(pool + gprev * 512 + col, run);
                    run = 0.f; gprev = g;
                }
                run += vv;
            }
            atomicAdd(pool + gprev * 512 + col, run);
        }
    }
    __syncthreads();

    #pragma unroll
    for (int i = 0; i < 4; ++i) {
        int e = t + i * 512;             // float4 slot
        int g = e >> 7, c4 = e & 127;
        int G = blk * NGROUPS + g;
        if (G < totalG) {
            float4 v = ((float4*)pool)[e];
            *(float4*)(out + (size_t)G * 1024 + 512 + c4 * 4) = v;
        }
    }
}

extern "C" void kernel_launch(void* const* d_in, const int* in_sizes, int n_in,
                              void* d_out, int out_size, void* d_ws, size_t ws_size,
                              hipStream_t stream) {
    const float* ctx = (const float*)d_in[0];
    const float* W1  = (const float*)d_in[1];
    const float* b1  = (const float*)d_in[2];
    const float* W2  = (const float*)d_in[3];
    const float* b2  = (const float*)d_in[4];
    const float* Wp  = (const float*)d_in[5];
    const float* bp  = (const float*)d_in[6];
    float* out = (float*)d_out;

    int B = in_sizes[0] / 28;
    // ws: 512 KB for transposed+swizzled bf16 W2 (16 ksteps x 512 n x 16 uints)
    prep_w2<<<32, 256, 0, stream>>>(W2, (uint*)d_ws);

    int total4 = B * 7 * 128;
    prop_kernel<<<(total4 + 255) / 256, 256, 0, stream>>>(ctx, Wp, bp, out, total4);

    int blocks = (B * 42 + MTILE - 1) / MTILE;
    rel_kernel<<<blocks, THREADS, 0, stream>>>(ctx, W1, b1, (const uint*)d_ws, b2, out, B);
}

// Round 5
// 805.091 us; speedup vs baseline: 2.7336x; 1.0758x over previous
//
#include <hip/hip_runtime.h>
#include <math.h>

typedef __attribute__((ext_vector_type(8))) short bf16x8;
typedef __attribute__((ext_vector_type(4))) float f32x4;

#define THREADS 512
#define MTILE 96
#define KSTEPS 16

// LDS byte offsets
#define OFF_HALL   0        // [16 ks][96 row][64 B] = 98304
#define OFF_W1B    98304    // [512 kh][32 f] bf16 = 32768
#define OFF_B1S    131072   // 512 f32 = 2048
#define OFF_FEATSB 133120   // [96 row][32 f] bf16 = 6144
#define LDS_TOTAL  139264
#define OFF_POOL   98304    // [16][512] f32 = 32768, aliases W1B (dead after prologue)

// RTN-even fp32 -> bf16 bits
__device__ __forceinline__ ushort f2bf(float f) {
    union { float f; uint u; } x; x.f = f;
    uint r = (x.u + 0x7fffu + ((x.u >> 16) & 1u)) >> 16;
    return (ushort)r;
}
__device__ __forceinline__ float bf2f(ushort u) {
    union { uint u; float f; } x; x.u = (uint)u << 16; return x.f;
}

// -------------------------------------------------------------------------
// prep: W2 (512x512 f32, [k][n]) -> w2t bf16 [kt][n][32 k] (natural k order).
// Slot (kt,n) = 64 B; sub-chunk q (0..3) holds k = kt*32 + q*8 .. +7.
// -------------------------------------------------------------------------
__global__ __launch_bounds__(256) void prep_w2(const float* __restrict__ W2,
                                               uint* __restrict__ w2t)
{
    int tid = blockIdx.x * 256 + threadIdx.x;   // 0..8191
    int kt = tid >> 9, n = tid & 511;
    uint* dst = w2t + (size_t)(kt * 512 + n) * 16;
    #pragma unroll
    for (int c = 0; c < 4; ++c) {
        uint q[4];
        #pragma unroll
        for (int j = 0; j < 4; ++j) {
            int k = kt * 32 + c * 8 + j * 2;
            float f0 = W2[(size_t)k * 512 + n];
            float f1 = W2[(size_t)(k + 1) * 512 + n];
            q[j] = (uint)f2bf(f0) | ((uint)f2bf(f1) << 16);
        }
        ((uint4*)dst)[c] = make_uint4(q[0], q[1], q[2], q[3]);
    }
}

// -------------------------------------------------------------------------
// rel: feats->h via MFMA (layer1, K=32 zero-padded), hAll fully in LDS,
// then barrier-free MFMA k-loop with register double-buffered B from L2.
// Epilogue: +b2, relu, mean-pool via LDS atomics, fused prop, store both.
// -------------------------------------------------------------------------
__global__ __launch_bounds__(THREADS, 2) void rel_kernel(
    const float* __restrict__ ctx, const float* __restrict__ W1,
    const float* __restrict__ b1, const uint* __restrict__ w2t,
    const float* __restrict__ b2, const float* __restrict__ Wp,
    const float* __restrict__ bp, float* __restrict__ out, int B)
{
    __shared__ __align__(16) char smem[LDS_TOTAL];
    const int t = threadIdx.x;
    const int wid = t >> 6, l = t & 63;
    const int wm = wid >> 2, wn = wid & 3;
    const int q = l >> 4, ln = l & 15;
    const int blk = blockIdx.x;
    const int totalG = B * 7;

    // ---- B prefetch: slabs 0,1 straight to registers (L2-resident) ----
    const char* wbase = (const char*)w2t + wn * 8192 + ln * 64 + q * 16;
    uint4 bA[8], bB[8];
    #pragma unroll
    for (int nf = 0; nf < 8; ++nf)
        bA[nf] = *(const uint4*)(wbase + nf * 1024);
    #pragma unroll
    for (int nf = 0; nf < 8; ++nf)
        bB[nf] = *(const uint4*)(wbase + 32768 + nf * 1024);

    // ---- stage W1b: bf16, transposed [k_h][32 f], f 9..31 zero ----
    {
        uint pk[16];
        #pragma unroll
        for (int u = 0; u < 16; ++u) pk[u] = 0u;
        #pragma unroll
        for (int f = 0; f < 9; ++f) {
            uint bv = f2bf(W1[f * 512 + t]);
            pk[f >> 1] |= (f & 1) ? (bv << 16) : bv;
        }
        uint4* dst = (uint4*)(smem + OFF_W1B + t * 64);
        dst[0] = make_uint4(pk[0],  pk[1],  pk[2],  pk[3]);
        dst[1] = make_uint4(pk[4],  pk[5],  pk[6],  pk[7]);
        dst[2] = make_uint4(pk[8],  pk[9],  pk[10], pk[11]);
        dst[3] = make_uint4(pk[12], pk[13], pk[14], pk[15]);
    }
    ((float*)(smem + OFF_B1S))[t] = b1[t];

    // ---- stage featsb: bf16 [row][32 f], f 9..31 zero ----
    if (t < MTILE) {
        int R = blk * MTILE + t;
        int G = R / 6, jj = R - G * 6;
        float ff[9];
        if (G < totalG) {
            int b = G / 7, i = G - b * 7;
            int j = jj + (jj >= i ? 1 : 0);
            const float* cb = ctx + (size_t)b * 28;
            float xi0=cb[i*4], xi1=cb[i*4+1], xi2=cb[i*4+2], xi3=cb[i*4+3];
            float xj0=cb[j*4], xj1=cb[j*4+1], xj2=cb[j*4+2], xj3=cb[j*4+3];
            float d0=xi0-xj0, d1=xi1-xj1, d2=xi2-xj2, d3=xi3-xj3;
            ff[0]=xi2; ff[1]=xi3; ff[2]=xj2; ff[3]=xj3;
            ff[4]=d0;  ff[5]=d1;  ff[6]=d2;  ff[7]=d3;
            ff[8]=sqrtf(d0*d0 + d1*d1);
        } else {
            #pragma unroll
            for (int f = 0; f < 9; ++f) ff[f] = 0.f;
        }
        uint pk[16];
        #pragma unroll
        for (int u = 0; u < 16; ++u) pk[u] = 0u;
        #pragma unroll
        for (int f = 0; f < 9; ++f) {
            uint bv = f2bf(ff[f]);
            pk[f >> 1] |= (f & 1) ? (bv << 16) : bv;
        }
        uint4* dst = (uint4*)(smem + OFF_FEATSB + t * 64);
        dst[0] = make_uint4(pk[0],  pk[1],  pk[2],  pk[3]);
        dst[1] = make_uint4(pk[4],  pk[5],  pk[6],  pk[7]);
        dst[2] = make_uint4(pk[8],  pk[9],  pk[10], pk[11]);
        dst[3] = make_uint4(pk[12], pk[13], pk[14], pk[15]);
    }
    __syncthreads();

    // ---- layer-1 via MFMA (swapped): D[k_h][row] = W1^T . feats^T ----
    // wave wid owns kh-tiles wid*4 .. wid*4+3, all 6 row-tiles.
    {
        bf16x8 fb[6];
        #pragma unroll
        for (int rt = 0; rt < 6; ++rt)
            fb[rt] = *(const bf16x8*)(smem + OFF_FEATSB + (rt*16 + ln)*64 + q*16);
        #pragma unroll
        for (int a = 0; a < 4; ++a) {
            int kt16 = wid * 4 + a;
            bf16x8 wa = *(const bf16x8*)(smem + OFF_W1B + (kt16*16 + ln)*64 + q*16);
            float4 bb = *(const float4*)(smem + OFF_B1S + (kt16*16 + q*4)*4);
            #pragma unroll
            for (int rt = 0; rt < 6; ++rt) {
                f32x4 d = __builtin_amdgcn_mfma_f32_16x16x32_bf16(
                    wa, fb[rt], (f32x4){0.f,0.f,0.f,0.f}, 0, 0, 0);
                uint p0 = (uint)f2bf(fmaxf(d[0]+bb.x, 0.f))
                        | ((uint)f2bf(fmaxf(d[1]+bb.y, 0.f)) << 16);
                uint p1 = (uint)f2bf(fmaxf(d[2]+bb.z, 0.f))
                        | ((uint)f2bf(fmaxf(d[3]+bb.w, 0.f)) << 16);
                int row = rt*16 + ln;
                char* dst = smem + OFF_HALL + (kt16 >> 1)*6144 + row*64
                          + (kt16 & 1)*32 + q*8;
                *(uint2*)dst = make_uint2(p0, p1);
            }
        }
    }
    __syncthreads();

    // ---- main k-loop: NO barriers; B double-buffered in registers ----
    f32x4 acc[3][8];
    #pragma unroll
    for (int mf = 0; mf < 3; ++mf)
        #pragma unroll
        for (int nf = 0; nf < 8; ++nf)
            acc[mf][nf] = (f32x4){0.f, 0.f, 0.f, 0.f};

    int aoff[3];
    #pragma unroll
    for (int mf = 0; mf < 3; ++mf)
        aoff[mf] = OFF_HALL + (wm*48 + mf*16 + ln)*64 + q*16;

    auto gstep = [&](int ks, uint4* bf) {
        bf16x8 a0 = *(const bf16x8*)(smem + aoff[0] + ks*6144);
        bf16x8 a1 = *(const bf16x8*)(smem + aoff[1] + ks*6144);
        bf16x8 a2 = *(const bf16x8*)(smem + aoff[2] + ks*6144);
        #pragma unroll
        for (int nf = 0; nf < 8; ++nf) {
            bf16x8 w = *(const bf16x8*)&bf[nf];
            acc[0][nf] = __builtin_amdgcn_mfma_f32_16x16x32_bf16(a0, w, acc[0][nf], 0,0,0);
            acc[1][nf] = __builtin_amdgcn_mfma_f32_16x16x32_bf16(a1, w, acc[1][nf], 0,0,0);
            acc[2][nf] = __builtin_amdgcn_mfma_f32_16x16x32_bf16(a2, w, acc[2][nf], 0,0,0);
        }
    };

    for (int kt = 0; kt < KSTEPS; kt += 2) {
        gstep(kt, bA);
        if (kt + 2 < KSTEPS) {
            #pragma unroll
            for (int nf = 0; nf < 8; ++nf)
                bA[nf] = *(const uint4*)(wbase + (kt+2)*32768 + nf*1024);
        }
        gstep(kt + 1, bB);
        if (kt + 3 < KSTEPS) {
            #pragma unroll
            for (int nf = 0; nf < 8; ++nf)
                bB[nf] = *(const uint4*)(wbase + (kt+3)*32768 + nf*1024);
        }
    }

    // ---- epilogue: +b2, relu, mean over 6 j's via LDS pool atomics ----
    float* pool = (float*)(smem + OFF_POOL);
    #pragma unroll
    for (int i = 0; i < 4; ++i)
        ((float4*)pool)[t + i*512] = make_float4(0.f, 0.f, 0.f, 0.f);
    __syncthreads();

    const float inv6 = 1.0f / 6.0f;
    #pragma unroll
    for (int mf = 0; mf < 3; ++mf) {
        int rbase = wm*48 + mf*16 + q*4;
        #pragma unroll
        for (int nf = 0; nf < 8; ++nf) {
            int col = wn*128 + nf*16 + ln;
            float bbv = b2[col];
            f32x4 a = acc[mf][nf];
            float run = 0.f;
            int gprev = rbase / 6;
            #pragma unroll
            for (int r = 0; r < 4; ++r) {
                int g = (rbase + r) / 6;
                float vv = fmaxf(a[r] + bbv, 0.f) * inv6;
                if (g != gprev) {
                    atomicAdd(pool + gprev*512 + col, run);
                    run = 0.f; gprev = g;
                }
                run += vv;
            }
            atomicAdd(pool + gprev*512 + col, run);
        }
    }
    __syncthreads();

    // ---- store: rel half from pool, prop half computed inline (fused) ----
    #pragma unroll
    for (int i = 0; i < 4; ++i) {
        int e = t + i*512;
        int g = e >> 7, c4 = e & 127;
        int G = blk * 16 + g;
        if (G < totalG) {
            float4 v = ((float4*)pool)[e];
            *(float4*)(out + (size_t)G*1024 + 512 + c4*4) = v;

            ushort u0 = *(const ushort*)(smem + OFF_FEATSB + (g*6)*64 + 0);
            ushort u1 = *(const ushort*)(smem + OFF_FEATSB + (g*6)*64 + 2);
            float a0 = bf2f(u0), a1 = bf2f(u1);
            float4 w0 = ((const float4*)Wp)[c4];
            float4 w1 = ((const float4*)(Wp + 512))[c4];
            float4 bv = ((const float4*)bp)[c4];
            float4 p;
            p.x = fmaxf(fmaf(a1, w1.x, fmaf(a0, w0.x, bv.x)), 0.f);
            p.y = fmaxf(fmaf(a1, w1.y, fmaf(a0, w0.y, bv.y)), 0.f);
            p.z = fmaxf(fmaf(a1, w1.z, fmaf(a0, w0.z, bv.z)), 0.f);
            p.w = fmaxf(fmaf(a1, w1.w, fmaf(a0, w0.w, bv.w)), 0.f);
            *(float4*)(out + (size_t)G*1024 + c4*4) = p;
        }
    }
}

extern "C" void kernel_launch(void* const* d_in, const int* in_sizes, int n_in,
                              void* d_out, int out_size, void* d_ws, size_t ws_size,
                              hipStream_t stream) {
    const float* ctx = (const float*)d_in[0];
    const float* W1  = (const float*)d_in[1];
    const float* b1  = (const float*)d_in[2];
    const float* W2  = (const float*)d_in[3];
    const float* b2  = (const float*)d_in[4];
    const float* Wp  = (const float*)d_in[5];
    const float* bp  = (const float*)d_in[6];
    float* out = (float*)d_out;

    int B = in_sizes[0] / 28;
    prep_w2<<<32, 256, 0, stream>>>(W2, (uint*)d_ws);   // 512 KB in d_ws

    int blocks = (B * 42 + MTILE - 1) / MTILE;
    rel_kernel<<<blocks, THREADS, 0, stream>>>(ctx, W1, b1, (const uint*)d_ws,
                                               b2, Wp, bp, out, B);
}

// Round 8
// 742.449 us; speedup vs baseline: 2.9643x; 1.0844x over previous
//
#include <hip/hip_runtime.h>
#include <math.h>

typedef __attribute__((ext_vector_type(8))) short bf16x8;
typedef __attribute__((ext_vector_type(4))) float f32x4;

#define THREADS 256
#define MTILE 48
#define KSTEPS 16

// LDS byte offsets (52.25 KB total -> 2 blocks/CU alongside reg budget)
#define OFF_HALL  0        // [16 ks][48 row][64 B] = 49152
#define OFF_FEATS 49152    // [48 row][32 f] bf16 = 3072
#define LDS_TOTAL 53248
#define OFF_POOL  0        // [8][512] f32 = 16384, aliases hAll (dead after k-loop)

// RTN-even fp32 -> bf16 bits
__device__ __forceinline__ ushort f2bf(float f) {
    union { float f; uint u; } x; x.f = f;
    uint r = (x.u + 0x7fffu + ((x.u >> 16) & 1u)) >> 16;
    return (ushort)r;
}
__device__ __forceinline__ float bf2f(ushort u) {
    union { uint u; float f; } x; x.u = (uint)u << 16; return x.f;
}

// -------------------------------------------------------------------------
// prep: W2 (512x512 f32, [k][n]) -> w2t bf16 [kt][n][32 k] (natural k order).
// Slot (kt,n) = 64 B; sub-chunk q (0..3) holds k = kt*32 + q*8 .. +7.
// -------------------------------------------------------------------------
__global__ __launch_bounds__(256) void prep_w2(const float* __restrict__ W2,
                                               uint* __restrict__ w2t)
{
    int tid = blockIdx.x * 256 + threadIdx.x;   // 0..8191
    int kt = tid >> 9, n = tid & 511;
    uint* dst = w2t + (size_t)(kt * 512 + n) * 16;
    #pragma unroll
    for (int c = 0; c < 4; ++c) {
        uint qv[4];
        #pragma unroll
        for (int j = 0; j < 4; ++j) {
            int k = kt * 32 + c * 8 + j * 2;
            float f0 = W2[(size_t)k * 512 + n];
            float f1 = W2[(size_t)(k + 1) * 512 + n];
            qv[j] = (uint)f2bf(f0) | ((uint)f2bf(f1) << 16);
        }
        ((uint4*)dst)[c] = make_uint4(qv[0], qv[1], qv[2], qv[3]);
    }
}

// -------------------------------------------------------------------------
// rel: 256 thr / 4 waves; MTILE=48 rows; wave owns 128 exclusive N-cols.
// Layer-1 h via MFMA with W1 A-frags built in regs (K=32 zero-padded).
// Main k-loop barrier-free, B 2-deep in regs, per-(block,wave) rotated kt
// order to spread L2 slab access. Epilogue: pool + fused prop.
// -------------------------------------------------------------------------
__global__ __launch_bounds__(THREADS, 2) void rel_kernel(
    const float* __restrict__ ctx, const float* __restrict__ W1,
    const float* __restrict__ b1, const uint* __restrict__ w2t,
    const float* __restrict__ b2, const float* __restrict__ Wp,
    const float* __restrict__ bp, float* __restrict__ out, int B)
{
    __shared__ __align__(16) char smem[LDS_TOTAL];
    const int t = threadIdx.x;
    const int wid = t >> 6, l = t & 63;
    const int q = l >> 4, ln = l & 15;
    const int blk = blockIdx.x;
    const int totalG = B * 7;

    // ---- B prefetch for rotated ksteps s=0,1 (latency hides under layer-1)
    const int kt0 = ((blk & 3) * 4 + wid + (blk >> 3)) & 15;
    const char* wbase = (const char*)w2t + (wid * 128 + ln) * 64 + q * 16;
    uint4 bA[8], bB[8];
    {
        int ka = kt0, kb = (kt0 + 1) & 15;
        #pragma unroll
        for (int nf = 0; nf < 8; ++nf)
            bA[nf] = *(const uint4*)(wbase + ka * 32768 + nf * 1024);
        #pragma unroll
        for (int nf = 0; nf < 8; ++nf)
            bB[nf] = *(const uint4*)(wbase + kb * 32768 + nf * 1024);
    }

    // ---- stage featsb: bf16 [row][32 f], f 9..31 zero ----
    if (t < MTILE) {
        int R = blk * MTILE + t;
        int G = R / 6, jj = R - G * 6;
        float ff[9];
        if (G < totalG) {
            int b = G / 7, i = G - b * 7;
            int j = jj + (jj >= i ? 1 : 0);
            const float* cb = ctx + (size_t)b * 28;
            float xi0=cb[i*4], xi1=cb[i*4+1], xi2=cb[i*4+2], xi3=cb[i*4+3];
            float xj0=cb[j*4], xj1=cb[j*4+1], xj2=cb[j*4+2], xj3=cb[j*4+3];
            float d0=xi0-xj0, d1=xi1-xj1, d2=xi2-xj2, d3=xi3-xj3;
            ff[0]=xi2; ff[1]=xi3; ff[2]=xj2; ff[3]=xj3;
            ff[4]=d0;  ff[5]=d1;  ff[6]=d2;  ff[7]=d3;
            ff[8]=sqrtf(d0*d0 + d1*d1);
        } else {
            #pragma unroll
            for (int f = 0; f < 9; ++f) ff[f] = 0.f;
        }
        uint pk[16];
        #pragma unroll
        for (int u = 0; u < 16; ++u) pk[u] = 0u;
        #pragma unroll
        for (int f = 0; f < 9; ++f) {
            uint bv = f2bf(ff[f]);
            pk[f >> 1] |= (f & 1) ? (bv << 16) : bv;
        }
        uint4* dst = (uint4*)(smem + OFF_FEATS + t * 64);
        dst[0] = make_uint4(pk[0],  pk[1],  pk[2],  pk[3]);
        dst[1] = make_uint4(pk[4],  pk[5],  pk[6],  pk[7]);
        dst[2] = make_uint4(pk[8],  pk[9],  pk[10], pk[11]);
        dst[3] = make_uint4(pk[12], pk[13], pk[14], pk[15]);
    }
    __syncthreads();

    // ---- layer-1 via MFMA (swapped): D[k_h][row] = W1^T . feats^T ----
    // wave wid owns kh-tiles wid*8 .. wid*8+7; A-frags from global W1 in regs.
    {
        bf16x8 fb[3];
        #pragma unroll
        for (int rt = 0; rt < 3; ++rt)
            fb[rt] = *(const bf16x8*)(smem + OFF_FEATS + (rt*16 + ln)*64 + q*16);
        #pragma unroll
        for (int a = 0; a < 8; ++a) {
            int kt16 = wid * 8 + a;
            int kh = kt16 * 16 + ln;
            // A-frag: features q*8+j (zero for f>=9)
            uint aw[4];
            #pragma unroll
            for (int jj2 = 0; jj2 < 4; ++jj2) {
                int f0 = q * 8 + jj2 * 2, f1 = f0 + 1;
                uint lo = (f0 < 9) ? (uint)f2bf(W1[f0 * 512 + kh]) : 0u;
                uint hi = (f1 < 9) ? (uint)f2bf(W1[f1 * 512 + kh]) : 0u;
                aw[jj2] = lo | (hi << 16);
            }
            bf16x8 wa;
            { uint4 tmp = make_uint4(aw[0], aw[1], aw[2], aw[3]);
              wa = *(bf16x8*)&tmp; }
            float4 bb = *(const float4*)(b1 + kt16 * 16 + q * 4);
            #pragma unroll
            for (int rt = 0; rt < 3; ++rt) {
                f32x4 d = __builtin_amdgcn_mfma_f32_16x16x32_bf16(
                    wa, fb[rt], (f32x4){0.f,0.f,0.f,0.f}, 0, 0, 0);
                uint p0 = (uint)f2bf(fmaxf(d[0]+bb.x, 0.f))
                        | ((uint)f2bf(fmaxf(d[1]+bb.y, 0.f)) << 16);
                uint p1 = (uint)f2bf(fmaxf(d[2]+bb.z, 0.f))
                        | ((uint)f2bf(fmaxf(d[3]+bb.w, 0.f)) << 16);
                int row = rt*16 + ln;
                char* dst = smem + OFF_HALL + (kt16 >> 1)*3072 + row*64
                          + (kt16 & 1)*32 + q*8;
                *(uint2*)dst = make_uint2(p0, p1);
            }
        }
    }
    __syncthreads();

    // ---- main k-loop: barrier-free; rotated kt order; B 2-deep in regs ----
    f32x4 acc[3][8];
    #pragma unroll
    for (int mf = 0; mf < 3; ++mf)
        #pragma unroll
        for (int nf = 0; nf < 8; ++nf)
            acc[mf][nf] = (f32x4){0.f, 0.f, 0.f, 0.f};

    int aoff[3];
    #pragma unroll
    for (int mf = 0; mf < 3; ++mf)
        aoff[mf] = OFF_HALL + (mf*16 + ln)*64 + q*16;

    auto gstep = [&](int ks, uint4* bf) {
        bf16x8 a0 = *(const bf16x8*)(smem + aoff[0] + ks*3072);
        bf16x8 a1 = *(const bf16x8*)(smem + aoff[1] + ks*3072);
        bf16x8 a2 = *(const bf16x8*)(smem + aoff[2] + ks*3072);
        #pragma unroll
        for (int nf = 0; nf < 8; ++nf) {
            bf16x8 w = *(const bf16x8*)&bf[nf];
            acc[0][nf] = __builtin_amdgcn_mfma_f32_16x16x32_bf16(a0, w, acc[0][nf], 0,0,0);
            acc[1][nf] = __builtin_amdgcn_mfma_f32_16x16x32_bf16(a1, w, acc[1][nf], 0,0,0);
            acc[2][nf] = __builtin_amdgcn_mfma_f32_16x16x32_bf16(a2, w, acc[2][nf], 0,0,0);
        }
    };

    #pragma unroll
    for (int s = 0; s < KSTEPS; s += 2) {
        gstep((kt0 + s) & 15, bA);
        if (s + 2 < KSTEPS) {
            int kn = (kt0 + s + 2) & 15;
            #pragma unroll
            for (int nf = 0; nf < 8; ++nf)
                bA[nf] = *(const uint4*)(wbase + kn * 32768 + nf * 1024);
        }
        gstep((kt0 + s + 1) & 15, bB);
        if (s + 3 < KSTEPS) {
            int kn = (kt0 + s + 3) & 15;
            #pragma unroll
            for (int nf = 0; nf < 8; ++nf)
                bB[nf] = *(const uint4*)(wbase + kn * 32768 + nf * 1024);
        }
    }

    // ---- epilogue: +b2, relu, mean over 6 j's via LDS pool atomics ----
    __syncthreads();                     // all hAll reads done; pool aliases it
    float* pool = (float*)(smem + OFF_POOL);
    #pragma unroll
    for (int i = 0; i < 4; ++i)
        ((float4*)pool)[t + i*256] = make_float4(0.f, 0.f, 0.f, 0.f);
    __syncthreads();

    const float inv6 = 1.0f / 6.0f;
    #pragma unroll
    for (int mf = 0; mf < 3; ++mf) {
        int rbase = mf*16 + q*4;
        #pragma unroll
        for (int nf = 0; nf < 8; ++nf) {
            int col = wid*128 + nf*16 + ln;
            float bbv = b2[col];
            f32x4 a = acc[mf][nf];
            float run = 0.f;
            int gprev = rbase / 6;
            #pragma unroll
            for (int r = 0; r < 4; ++r) {
                int g = (rbase + r) / 6;
                float vv = fmaxf(a[r] + bbv, 0.f) * inv6;
                if (g != gprev) {
                    atomicAdd(pool + gprev*512 + col, run);
                    run = 0.f; gprev = g;
                }
                run += vv;
            }
            atomicAdd(pool + gprev*512 + col, run);
        }
    }
    __syncthreads();

    // ---- store: rel half from pool, prop half computed inline (fused) ----
    #pragma unroll
    for (int i = 0; i < 4; ++i) {
        int e = t + i*256;               // float4 slot, 1024 total = 8 grp x 128
        int g = e >> 7, c4 = e & 127;
        int G = blk * 8 + g;
        if (G < totalG) {
            float4 v = ((float4*)pool)[e];
            *(float4*)(out + (size_t)G*1024 + 512 + c4*4) = v;

            ushort u0 = *(const ushort*)(smem + OFF_FEATS + (g*6)*64 + 0);
            ushort u1 = *(const ushort*)(smem + OFF_FEATS + (g*6)*64 + 2);
            float a0 = bf2f(u0), a1 = bf2f(u1);
            float4 w0 = ((const float4*)Wp)[c4];
            float4 w1 = ((const float4*)(Wp + 512))[c4];
            float4 bv = ((const float4*)bp)[c4];
            float4 p;
            p.x = fmaxf(fmaf(a1, w1.x, fmaf(a0, w0.x, bv.x)), 0.f);
            p.y = fmaxf(fmaf(a1, w1.y, fmaf(a0, w0.y, bv.y)), 0.f);
            p.z = fmaxf(fmaf(a1, w1.z, fmaf(a0, w0.z, bv.z)), 0.f);
            p.w = fmaxf(fmaf(a1, w1.w, fmaf(a0, w0.w, bv.w)), 0.f);
            *(float4*)(out + (size_t)G*1024 + c4*4) = p;
        }
    }
}

extern "C" void kernel_launch(void* const* d_in, const int* in_sizes, int n_in,
                              void* d_out, int out_size, void* d_ws, size_t ws_size,
                              hipStream_t stream) {
    const float* ctx = (const float*)d_in[0];
    const float* W1  = (const float*)d_in[1];
    const float* b1  = (const float*)d_in[2];
    const float* W2  = (const float*)d_in[3];
    const float* b2  = (const float*)d_in[4];
    const float* Wp  = (const float*)d_in[5];
    const float* bp  = (const float*)d_in[6];
    float* out = (float*)d_out;

    int B = in_sizes[0] / 28;
    prep_w2<<<32, 256, 0, stream>>>(W2, (uint*)d_ws);   // 512 KB in d_ws

    int blocks = (B * 42 + MTILE - 1) / MTILE;
    rel_kernel<<<blocks, THREADS, 0, stream>>>(ctx, W1, b1, (const uint*)d_ws,
                                               b2, Wp, bp, out, B);
}